// Round 3
// baseline (500.654 us; speedup 1.0000x reference)
//
#include <hip/hip_runtime.h>
#include <hip/hip_fp16.h>

typedef _Float16 half8 __attribute__((ext_vector_type(8)));
typedef float floatx4 __attribute__((ext_vector_type(4)));

#define AS1 __attribute__((address_space(1)))
#define AS3 __attribute__((address_space(3)))

// d_ws layout (halfs):
//   [0, WLO_OFF)            W hi, fragment order
//   [WLO_OFF, 2*WLO_OFF)    W lo
//   [XH_BASE, +XH_LO_OFF)   x|h hi, fragment order (mat 0 = x, 1 = h)
//   [XH_BASE+XH_LO_OFF, ..) x|h lo
#define WLO_OFF   (6 * 512 * 512)                        // 1,572,864
#define XH_BASE   (2 * WLO_OFF)                          // 3,145,728
#define XH_LO_OFF (2 * 16384 * 512)                      // 16,777,216
#define WS_NEED   ((size_t)(XH_BASE + 2 * XH_LO_OFF) * 2) // 73,400,320 B

__device__ __forceinline__ void async_lds16(const void* g, void* l) {
  __builtin_amdgcn_global_load_lds((const AS1 void*)g, (AS3 void*)l, 16, 0, 0);
}

// ---------------------------------------------------------------------------
// Pre-pass: W (6 matrices) and x/h -> fp16 hi/lo in MFMA fragment order.
// W tile (w, nt, ki): 4096 B; chunk (u,l) at u*1024+l*16 holds
//   B[k0+8*(l>>4)+j][n0+16*u+(l&15)], j=0..7.
// x/h tile (mat, mt, kt): 8192 B; chunk c (0..511) at c*16 holds
//   A[m0+16*(c>>6)+(c&15)][k0+8*((c&63)>>4)+j], j=0..7  (A-fragment order).
// ---------------------------------------------------------------------------
__global__ __launch_bounds__(256) void preprocess(
    const float* __restrict__ x, const float* __restrict__ h,
    const float* __restrict__ Wir, const float* __restrict__ Whr,
    const float* __restrict__ Wiz, const float* __restrict__ Whz,
    const float* __restrict__ Win, const float* __restrict__ Whn,
    _Float16* __restrict__ ws, int do_xh) {
  const int t = threadIdx.x;
  const int bid = blockIdx.x;
  if (do_xh && bid < 4096) {
    // ---- x/h: 8 consecutive k-floats of one row are contiguous in global,
    // so gather directly (no LDS round-trip). Stores fully coalesced.
    const int mat = bid >> 11;
    const int rem = bid & 2047;
    const int mt = rem >> 4, kt = rem & 15;
    const float* src = mat ? h : x;
    const size_t tb = (size_t)(mat * 2048 + mt * 16 + kt) * 4096;
    _Float16* hi = ws + XH_BASE;
    _Float16* lo = hi + XH_LO_OFF;
#pragma unroll
    for (int cc = 0; cc < 2; ++cc) {
      const int c = t + cc * 256;
      const int l = c & 63, s = c >> 6;
      const int m = mt * 128 + 16 * s + (l & 15);
      const int k = kt * 32 + 8 * (l >> 4);
      const float* p = src + (size_t)m * 512 + k;
      float4 f0 = *(const float4*)p;
      float4 f1 = *(const float4*)(p + 4);
      float v[8] = {f0.x, f0.y, f0.z, f0.w, f1.x, f1.y, f1.z, f1.w};
      half8 vh, vl;
#pragma unroll
      for (int j = 0; j < 8; ++j) {
        _Float16 a = (_Float16)v[j];
        vh[j] = a;
        vl[j] = (_Float16)(v[j] - (float)a);
      }
      *(half8*)(hi + tb + c * 8) = vh;
      *(half8*)(lo + tb + c * 8) = vl;
    }
    return;
  }
  // ---- W permute (proven in R2) ----
  const int b = do_xh ? (bid - 4096) : bid;
  __shared__ __align__(16) float tile[32 * 68];
  const int w = b >> 7;
  const int rem = b & 127;
  const int ki = rem >> 3;
  const int nt = rem & 7;
  const float* W = (w == 0) ? Wir : (w == 1) ? Whr : (w == 2) ? Wiz
                 : (w == 3) ? Whz : (w == 4) ? Win : Whn;
  const int k0 = ki * 32, n0 = nt * 64;
  const int kk = t >> 3;
  const int nn = (t & 7) * 8;
  const float* src = W + (k0 + kk) * 512 + n0 + nn;
  float4 f0 = *(const float4*)(src);
  float4 f1 = *(const float4*)(src + 4);
  float* drow = tile + kk * 68 + nn;
  *(float4*)(drow) = f0;
  *(float4*)(drow + 4) = f1;
  __syncthreads();
  const int u = t >> 6, l = t & 63;
  const int nloc = 16 * u + (l & 15);
  const int kbase = 8 * (l >> 4);
  half8 vh, vl;
#pragma unroll
  for (int j = 0; j < 8; ++j) {
    float f = tile[(kbase + j) * 68 + nloc];
    _Float16 hiv = (_Float16)f;
    vh[j] = hiv;
    vl[j] = (_Float16)(f - (float)hiv);
  }
  const size_t off = ((size_t)((w * 8 + nt) * 16 + ki)) * 2048 + t * 8;
  *(half8*)(ws + off) = vh;
  *(half8*)(ws + WLO_OFF + off) = vl;
}

// ---------------------------------------------------------------------------
// XCD swizzle: blocks dispatch round-robin over 8 XCDs by bid. Make the 8
// nt-blocks sharing an m-strip land consecutively on ONE XCD so x/h tiles are
// fetched once per XCD and hit L2 afterwards.
// ---------------------------------------------------------------------------
__device__ __forceinline__ void swizzle_mn(int bid, int& mt, int& nt) {
  const int xcd = bid & 7;
  const int u = bid >> 3;
  nt = u & 7;
  mt = ((u >> 3) << 3) | xcd;
}

// ---------------------------------------------------------------------------
// Primary fused GRU: ALL staging via global_load_lds width-16 (no VALU in the
// staging path). Block tile 128x64, 4 waves of 64x32, BK=32, hi/lo 3-term
// fp16 MFMA emulation. W_lo fragments read direct global->VGPR.
// ---------------------------------------------------------------------------
__global__ __launch_bounds__(256, 2) void gru_dma(
    const float* __restrict__ h, const _Float16* __restrict__ ws,
    const float* __restrict__ br, const float* __restrict__ bz,
    const float* __restrict__ bn, float* __restrict__ out) {
  __shared__ __align__(16) _Float16 ldsXh[4096];   // 8 KB each
  __shared__ __align__(16) _Float16 ldsXl[4096];
  __shared__ __align__(16) _Float16 ldsHh[4096];
  __shared__ __align__(16) _Float16 ldsHl[4096];
  __shared__ __align__(16) _Float16 ldsW[6 * 2048]; // 24 KB

  const int t = threadIdx.x;
  const int lane = t & 63;
  const int wv = t >> 6;
  const int wm = wv >> 1;
  const int wn = wv & 1;
  int mt, nt;
  swizzle_mn(blockIdx.x, mt, nt);
  const int m0 = mt * 128;
  const int n0 = nt * 64;

  const _Float16* whi = ws;
  const _Float16* wlo = ws + WLO_OFF;
  const _Float16* xhhi = ws + XH_BASE;
  const _Float16* xhlo = xhhi + XH_LO_OFF;

  floatx4 acc_r[4][2] = {};
  floatx4 acc_z[4][2] = {};
  floatx4 acc_in[4][2] = {};
  floatx4 acc_hn[4][2] = {};

  for (int kt = 0; kt < 16; ++kt) {
    __syncthreads();  // previous iter's LDS reads complete before overwrite

    // 56 KB of staging = 56 wave-calls of 1 KB; 14 per wave.
#pragma unroll
    for (int q = 0; q < 14; ++q) {
      const int g = wv * 14 + q;
      const char* gsrc;
      char* ldst;
      if (g < 24) {  // W hi: 6 tiles x 4 KB
        const int w = g >> 2, uu = g & 3;
        gsrc = (const char*)whi + ((size_t)((w * 8 + nt) * 16 + kt)) * 4096 +
               uu * 1024 + (size_t)lane * 16;
        ldst = (char*)ldsW + (w * 4 + uu) * 1024;
      } else {       // x/h hi/lo: 4 bufs x 8 KB
        const int g2 = g - 24;
        const int buf = g2 >> 3, seg = g2 & 7;
        const int mat = buf >> 1;   // 0: x, 1: h
        const int part = buf & 1;   // 0: hi, 1: lo
        const _Float16* base = part ? xhlo : xhhi;
        gsrc = (const char*)base + ((size_t)(mat * 2048 + mt * 16 + kt)) * 8192 +
               seg * 1024 + (size_t)lane * 16;
        _Float16* lb = (buf == 0) ? ldsXh : (buf == 1) ? ldsXl
                     : (buf == 2) ? ldsHh : ldsHl;
        ldst = (char*)lb + seg * 1024;
      }
      async_lds16(gsrc, ldst);
    }
    __syncthreads();  // drains vmcnt for all staging DMAs

    // --- compute: 144 MFMA / wave / k-step ---
    half8 axh[4], ahh[4];
#pragma unroll
    for (int i = 0; i < 4; ++i) {
      axh[i] = *(const half8*)(ldsXh + ((wm * 4 + i) * 64 + lane) * 8);
      ahh[i] = *(const half8*)(ldsHh + ((wm * 4 + i) * 64 + lane) * 8);
    }
#pragma unroll
    for (int jn = 0; jn < 2; ++jn) {
      const int bo = (wn * 2 + jn) * 512 + lane * 8;
      const size_t tb = ((size_t)(nt * 16 + kt)) * 2048 + bo;
      half8 bl_ir = *(const half8*)(wlo + tb + (size_t)0 * 8 * 16 * 2048);
      half8 bl_hr = *(const half8*)(wlo + tb + (size_t)1 * 8 * 16 * 2048);
      half8 bl_iz = *(const half8*)(wlo + tb + (size_t)2 * 8 * 16 * 2048);
      half8 bl_hz = *(const half8*)(wlo + tb + (size_t)3 * 8 * 16 * 2048);
      half8 bl_in = *(const half8*)(wlo + tb + (size_t)4 * 8 * 16 * 2048);
      half8 bl_hn = *(const half8*)(wlo + tb + (size_t)5 * 8 * 16 * 2048);
      half8 bh_ir = *(const half8*)(ldsW + 0 * 2048 + bo);
      half8 bh_hr = *(const half8*)(ldsW + 1 * 2048 + bo);
      half8 bh_iz = *(const half8*)(ldsW + 2 * 2048 + bo);
      half8 bh_hz = *(const half8*)(ldsW + 3 * 2048 + bo);
      half8 bh_in = *(const half8*)(ldsW + 4 * 2048 + bo);
      half8 bh_hn = *(const half8*)(ldsW + 5 * 2048 + bo);
#pragma unroll
      for (int i = 0; i < 4; ++i) {
        half8 axl = *(const half8*)(ldsXl + ((wm * 4 + i) * 64 + lane) * 8);
        half8 ahl = *(const half8*)(ldsHl + ((wm * 4 + i) * 64 + lane) * 8);
        acc_r[i][jn]  = __builtin_amdgcn_mfma_f32_16x16x32_f16(axh[i], bh_ir, acc_r[i][jn], 0, 0, 0);
        acc_r[i][jn]  = __builtin_amdgcn_mfma_f32_16x16x32_f16(axl,    bh_ir, acc_r[i][jn], 0, 0, 0);
        acc_r[i][jn]  = __builtin_amdgcn_mfma_f32_16x16x32_f16(ahh[i], bh_hr, acc_r[i][jn], 0, 0, 0);
        acc_r[i][jn]  = __builtin_amdgcn_mfma_f32_16x16x32_f16(ahl,    bh_hr, acc_r[i][jn], 0, 0, 0);
        acc_z[i][jn]  = __builtin_amdgcn_mfma_f32_16x16x32_f16(axh[i], bh_iz, acc_z[i][jn], 0, 0, 0);
        acc_z[i][jn]  = __builtin_amdgcn_mfma_f32_16x16x32_f16(axl,    bh_iz, acc_z[i][jn], 0, 0, 0);
        acc_z[i][jn]  = __builtin_amdgcn_mfma_f32_16x16x32_f16(ahh[i], bh_hz, acc_z[i][jn], 0, 0, 0);
        acc_z[i][jn]  = __builtin_amdgcn_mfma_f32_16x16x32_f16(ahl,    bh_hz, acc_z[i][jn], 0, 0, 0);
        acc_in[i][jn] = __builtin_amdgcn_mfma_f32_16x16x32_f16(axh[i], bh_in, acc_in[i][jn], 0, 0, 0);
        acc_in[i][jn] = __builtin_amdgcn_mfma_f32_16x16x32_f16(axl,    bh_in, acc_in[i][jn], 0, 0, 0);
        acc_hn[i][jn] = __builtin_amdgcn_mfma_f32_16x16x32_f16(ahh[i], bh_hn, acc_hn[i][jn], 0, 0, 0);
        acc_hn[i][jn] = __builtin_amdgcn_mfma_f32_16x16x32_f16(ahl,    bh_hn, acc_hn[i][jn], 0, 0, 0);
      }
#pragma unroll
      for (int i = 0; i < 4; ++i) {
        acc_r[i][jn]  = __builtin_amdgcn_mfma_f32_16x16x32_f16(axh[i], bl_ir, acc_r[i][jn], 0, 0, 0);
        acc_r[i][jn]  = __builtin_amdgcn_mfma_f32_16x16x32_f16(ahh[i], bl_hr, acc_r[i][jn], 0, 0, 0);
        acc_z[i][jn]  = __builtin_amdgcn_mfma_f32_16x16x32_f16(axh[i], bl_iz, acc_z[i][jn], 0, 0, 0);
        acc_z[i][jn]  = __builtin_amdgcn_mfma_f32_16x16x32_f16(ahh[i], bl_hz, acc_z[i][jn], 0, 0, 0);
        acc_in[i][jn] = __builtin_amdgcn_mfma_f32_16x16x32_f16(axh[i], bl_in, acc_in[i][jn], 0, 0, 0);
        acc_hn[i][jn] = __builtin_amdgcn_mfma_f32_16x16x32_f16(ahh[i], bl_hn, acc_hn[i][jn], 0, 0, 0);
      }
    }
  }

  const int quad = lane >> 4;
  const int col = lane & 15;
#pragma unroll
  for (int i = 0; i < 4; ++i) {
    const int mbase = m0 + wm * 64 + i * 16 + quad * 4;
#pragma unroll
    for (int jn = 0; jn < 2; ++jn) {
      const int n = n0 + wn * 32 + jn * 16 + col;
      const float vbr = br[n], vbz = bz[n], vbn = bn[n];
#pragma unroll
      for (int r = 0; r < 4; ++r) {
        const int m = mbase + r;
        const float gr = acc_r[i][jn][r] + vbr;
        const float gz = acc_z[i][jn][r] + vbz;
        const float rg = 1.0f / (1.0f + __expf(-gr));
        const float zg = 1.0f / (1.0f + __expf(-gz));
        const float gn = acc_in[i][jn][r] + rg * acc_hn[i][jn][r] + vbn;
        const float e2 = __expf(2.0f * gn);
        const float ntv = 1.0f - 2.0f / (e2 + 1.0f);
        const float hp = h[m * 512 + n];
        out[m * 512 + n] = (1.0f - zg) * ntv + zg * hp;
      }
    }
  }
}

// ---------------------------------------------------------------------------
// Fallback (ws too small for x/h pre-pass): R2-proven kernel + XCD swizzle.
// ---------------------------------------------------------------------------
__global__ __launch_bounds__(256, 2) void gru_conv(
    const float* __restrict__ x, const float* __restrict__ h,
    const _Float16* __restrict__ wperm,
    const float* __restrict__ br, const float* __restrict__ bz,
    const float* __restrict__ bn, float* __restrict__ out) {
  __shared__ __align__(16) _Float16 ldsXh[128 * 32];
  __shared__ __align__(16) _Float16 ldsXl[128 * 32];
  __shared__ __align__(16) _Float16 ldsHh[128 * 32];
  __shared__ __align__(16) _Float16 ldsHl[128 * 32];
  __shared__ __align__(16) _Float16 ldsW[6 * 2048];

  const int t = threadIdx.x;
  const int lane = t & 63;
  const int wv = t >> 6;
  const int wm = wv >> 1;
  const int wn = wv & 1;
  int mt, nt;
  swizzle_mn(blockIdx.x, mt, nt);
  const int m0 = mt * 128;
  const int n0 = nt * 64;
  const _Float16* wlo = wperm + WLO_OFF;

  floatx4 acc_r[4][2] = {};
  floatx4 acc_z[4][2] = {};
  floatx4 acc_in[4][2] = {};
  floatx4 acc_hn[4][2] = {};

  const int c0 = t, c1 = t + 256;
  const int s0 = c0 >> 6, l0 = c0 & 63;
  const int s1 = c1 >> 6, l1 = c1 & 63;
  const int mA0 = 16 * s0 + (l0 & 15), kA0 = 8 * (l0 >> 4);
  const int mA1 = 16 * s1 + (l1 & 15), kA1 = 8 * (l1 >> 4);

  for (int kt = 0; kt < 16; ++kt) {
    const int k0 = kt * 32;
    __syncthreads();
#pragma unroll
    for (int q = 0; q < 6; ++q) {
      const int gg = wv * 6 + q;
      const int w = gg >> 2, u = gg & 3;
      const char* gsrc = (const char*)wperm +
          ((size_t)((w * 8 + nt) * 16 + kt)) * 4096 + u * 1024 + lane * 16;
      char* ldst = (char*)ldsW + (w * 4 + u) * 1024;
      async_lds16(gsrc, ldst);
    }
    {
      const float* px0 = x + (m0 + mA0) * 512 + k0 + kA0;
      const float* px1 = x + (m0 + mA1) * 512 + k0 + kA1;
      const float* ph0 = h + (m0 + mA0) * 512 + k0 + kA0;
      const float* ph1 = h + (m0 + mA1) * 512 + k0 + kA1;
      float v[4][8];
      *(float4*)&v[0][0] = *(const float4*)px0; *(float4*)&v[0][4] = *(const float4*)(px0 + 4);
      *(float4*)&v[1][0] = *(const float4*)px1; *(float4*)&v[1][4] = *(const float4*)(px1 + 4);
      *(float4*)&v[2][0] = *(const float4*)ph0; *(float4*)&v[2][4] = *(const float4*)(ph0 + 4);
      *(float4*)&v[3][0] = *(const float4*)ph1; *(float4*)&v[3][4] = *(const float4*)(ph1 + 4);
      half8 hi[4], lo[4];
#pragma unroll
      for (int g = 0; g < 4; ++g) {
#pragma unroll
        for (int j = 0; j < 8; ++j) {
          _Float16 a = (_Float16)v[g][j];
          hi[g][j] = a;
          lo[g][j] = (_Float16)(v[g][j] - (float)a);
        }
      }
      *(half8*)(ldsXh + c0 * 8) = hi[0]; *(half8*)(ldsXl + c0 * 8) = lo[0];
      *(half8*)(ldsXh + c1 * 8) = hi[1]; *(half8*)(ldsXl + c1 * 8) = lo[1];
      *(half8*)(ldsHh + c0 * 8) = hi[2]; *(half8*)(ldsHl + c0 * 8) = lo[2];
      *(half8*)(ldsHh + c1 * 8) = hi[3]; *(half8*)(ldsHl + c1 * 8) = lo[3];
    }
    __syncthreads();

    half8 axh[4], ahh[4];
#pragma unroll
    for (int i = 0; i < 4; ++i) {
      axh[i] = *(const half8*)(ldsXh + ((wm * 4 + i) * 64 + lane) * 8);
      ahh[i] = *(const half8*)(ldsHh + ((wm * 4 + i) * 64 + lane) * 8);
    }
#pragma unroll
    for (int jn = 0; jn < 2; ++jn) {
      const int bo = (wn * 2 + jn) * 512 + lane * 8;
      const size_t tb = ((size_t)(nt * 16 + kt)) * 2048 + bo;
      half8 bl_ir = *(const half8*)(wlo + tb + (size_t)0 * 8 * 16 * 2048);
      half8 bl_hr = *(const half8*)(wlo + tb + (size_t)1 * 8 * 16 * 2048);
      half8 bl_iz = *(const half8*)(wlo + tb + (size_t)2 * 8 * 16 * 2048);
      half8 bl_hz = *(const half8*)(wlo + tb + (size_t)3 * 8 * 16 * 2048);
      half8 bl_in = *(const half8*)(wlo + tb + (size_t)4 * 8 * 16 * 2048);
      half8 bl_hn = *(const half8*)(wlo + tb + (size_t)5 * 8 * 16 * 2048);
      half8 bh_ir = *(const half8*)(ldsW + 0 * 2048 + bo);
      half8 bh_hr = *(const half8*)(ldsW + 1 * 2048 + bo);
      half8 bh_iz = *(const half8*)(ldsW + 2 * 2048 + bo);
      half8 bh_hz = *(const half8*)(ldsW + 3 * 2048 + bo);
      half8 bh_in = *(const half8*)(ldsW + 4 * 2048 + bo);
      half8 bh_hn = *(const half8*)(ldsW + 5 * 2048 + bo);
#pragma unroll
      for (int i = 0; i < 4; ++i) {
        half8 axl = *(const half8*)(ldsXl + ((wm * 4 + i) * 64 + lane) * 8);
        half8 ahl = *(const half8*)(ldsHl + ((wm * 4 + i) * 64 + lane) * 8);
        acc_r[i][jn]  = __builtin_amdgcn_mfma_f32_16x16x32_f16(axh[i], bh_ir, acc_r[i][jn], 0, 0, 0);
        acc_r[i][jn]  = __builtin_amdgcn_mfma_f32_16x16x32_f16(axl,    bh_ir, acc_r[i][jn], 0, 0, 0);
        acc_r[i][jn]  = __builtin_amdgcn_mfma_f32_16x16x32_f16(ahh[i], bh_hr, acc_r[i][jn], 0, 0, 0);
        acc_r[i][jn]  = __builtin_amdgcn_mfma_f32_16x16x32_f16(ahl,    bh_hr, acc_r[i][jn], 0, 0, 0);
        acc_z[i][jn]  = __builtin_amdgcn_mfma_f32_16x16x32_f16(axh[i], bh_iz, acc_z[i][jn], 0, 0, 0);
        acc_z[i][jn]  = __builtin_amdgcn_mfma_f32_16x16x32_f16(axl,    bh_iz, acc_z[i][jn], 0, 0, 0);
        acc_z[i][jn]  = __builtin_amdgcn_mfma_f32_16x16x32_f16(ahh[i], bh_hz, acc_z[i][jn], 0, 0, 0);
        acc_z[i][jn]  = __builtin_amdgcn_mfma_f32_16x16x32_f16(ahl,    bh_hz, acc_z[i][jn], 0, 0, 0);
        acc_in[i][jn] = __builtin_amdgcn_mfma_f32_16x16x32_f16(axh[i], bh_in, acc_in[i][jn], 0, 0, 0);
        acc_in[i][jn] = __builtin_amdgcn_mfma_f32_16x16x32_f16(axl,    bh_in, acc_in[i][jn], 0, 0, 0);
        acc_hn[i][jn] = __builtin_amdgcn_mfma_f32_16x16x32_f16(ahh[i], bh_hn, acc_hn[i][jn], 0, 0, 0);
        acc_hn[i][jn] = __builtin_amdgcn_mfma_f32_16x16x32_f16(ahl,    bh_hn, acc_hn[i][jn], 0, 0, 0);
      }
#pragma unroll
      for (int i = 0; i < 4; ++i) {
        acc_r[i][jn]  = __builtin_amdgcn_mfma_f32_16x16x32_f16(axh[i], bl_ir, acc_r[i][jn], 0, 0, 0);
        acc_r[i][jn]  = __builtin_amdgcn_mfma_f32_16x16x32_f16(ahh[i], bl_hr, acc_r[i][jn], 0, 0, 0);
        acc_z[i][jn]  = __builtin_amdgcn_mfma_f32_16x16x32_f16(axh[i], bl_iz, acc_z[i][jn], 0, 0, 0);
        acc_z[i][jn]  = __builtin_amdgcn_mfma_f32_16x16x32_f16(ahh[i], bl_hz, acc_z[i][jn], 0, 0, 0);
        acc_in[i][jn] = __builtin_amdgcn_mfma_f32_16x16x32_f16(axh[i], bl_in, acc_in[i][jn], 0, 0, 0);
        acc_hn[i][jn] = __builtin_amdgcn_mfma_f32_16x16x32_f16(ahh[i], bl_hn, acc_hn[i][jn], 0, 0, 0);
      }
    }
  }

  const int quad = lane >> 4;
  const int col = lane & 15;
#pragma unroll
  for (int i = 0; i < 4; ++i) {
    const int mbase = m0 + wm * 64 + i * 16 + quad * 4;
#pragma unroll
    for (int jn = 0; jn < 2; ++jn) {
      const int n = n0 + wn * 32 + jn * 16 + col;
      const float vbr = br[n], vbz = bz[n], vbn = bn[n];
#pragma unroll
      for (int r = 0; r < 4; ++r) {
        const int m = mbase + r;
        const float gr = acc_r[i][jn][r] + vbr;
        const float gz = acc_z[i][jn][r] + vbz;
        const float rg = 1.0f / (1.0f + __expf(-gr));
        const float zg = 1.0f / (1.0f + __expf(-gz));
        const float gn = acc_in[i][jn][r] + rg * acc_hn[i][jn][r] + vbn;
        const float e2 = __expf(2.0f * gn);
        const float ntv = 1.0f - 2.0f / (e2 + 1.0f);
        const float hp = h[m * 512 + n];
        out[m * 512 + n] = (1.0f - zg) * ntv + zg * hp;
      }
    }
  }
}

extern "C" void kernel_launch(void* const* d_in, const int* in_sizes, int n_in,
                              void* d_out, int out_size, void* d_ws, size_t ws_size,
                              hipStream_t stream) {
  const float* x   = (const float*)d_in[0];
  const float* h   = (const float*)d_in[1];
  const float* Wir = (const float*)d_in[2];
  const float* Whr = (const float*)d_in[3];
  const float* br  = (const float*)d_in[4];
  const float* Wiz = (const float*)d_in[5];
  const float* Whz = (const float*)d_in[6];
  const float* bz  = (const float*)d_in[7];
  const float* Win = (const float*)d_in[8];
  const float* Whn = (const float*)d_in[9];
  const float* bn  = (const float*)d_in[10];
  float* out = (float*)d_out;
  _Float16* ws = (_Float16*)d_ws;

  if (ws_size >= WS_NEED) {
    preprocess<<<4096 + 768, 256, 0, stream>>>(x, h, Wir, Whr, Wiz, Whz, Win, Whn, ws, 1);
    gru_dma<<<1024, 256, 0, stream>>>(h, ws, br, bz, bn, out);
  } else {
    preprocess<<<768, 256, 0, stream>>>(x, h, Wir, Whr, Wiz, Whz, Win, Whn, ws, 0);
    gru_conv<<<1024, 256, 0, stream>>>(x, h, ws, br, bz, bn, out);
  }
}

// Round 4
// 286.213 us; speedup vs baseline: 1.7492x; 1.7492x over previous
//
#include <hip/hip_runtime.h>
#include <hip/hip_fp16.h>

typedef _Float16 half8 __attribute__((ext_vector_type(8)));
typedef float floatx4 __attribute__((ext_vector_type(4)));

// wperm layout (halfs): hi at [0, WLO_OFF), lo at [WLO_OFF, 2*WLO_OFF)
#define WLO_OFF (6 * 512 * 512)
#define WSTRIDE ((size_t)(8 * 16 * 2048))  // per-W-matrix stride in halfs

// ---------------------------------------------------------------------------
// P1: 6 W matrices [512(k) x 512(n)] fp32 -> fp16 hi + lo (lo = fp16(W - hi),
// ~22-bit effective mantissa), MFMA B-fragment order: tile(w, nt, ki) is
// 4096 B; chunk (u,l) at u*1024 + l*16 holds B[k0+8*(l>>4)+j][n0+16u+(l&15)].
// ---------------------------------------------------------------------------
__global__ __launch_bounds__(256) void permute_w(
    const float* __restrict__ Wir, const float* __restrict__ Whr,
    const float* __restrict__ Wiz, const float* __restrict__ Whz,
    const float* __restrict__ Win, const float* __restrict__ Whn,
    _Float16* __restrict__ wperm) {
  __shared__ __align__(16) float tile[32 * 68];
  const int b = blockIdx.x;
  const int w = b >> 7;
  const int rem = b & 127;
  const int ki = rem >> 3;
  const int nt = rem & 7;
  const float* W = (w == 0) ? Wir : (w == 1) ? Whr : (w == 2) ? Wiz
                 : (w == 3) ? Whz : (w == 4) ? Win : Whn;
  const int k0 = ki * 32, n0 = nt * 64;
  const int t = threadIdx.x;

  const int kk = t >> 3;
  const int nn = (t & 7) * 8;
  const float* src = W + (k0 + kk) * 512 + n0 + nn;
  float4 f0 = *(const float4*)(src);
  float4 f1 = *(const float4*)(src + 4);
  float* drow = tile + kk * 68 + nn;
  *(float4*)(drow) = f0;
  *(float4*)(drow + 4) = f1;
  __syncthreads();

  const int u = t >> 6, l = t & 63;
  const int nloc = 16 * u + (l & 15);
  const int kbase = 8 * (l >> 4);
  half8 vh, vl;
#pragma unroll
  for (int j = 0; j < 8; ++j) {
    float f = tile[(kbase + j) * 68 + nloc];
    _Float16 hiv = (_Float16)f;
    vh[j] = hiv;
    vl[j] = (_Float16)(f - (float)hiv);
  }
  const size_t off = ((size_t)((w * 8 + nt) * 16 + ki)) * 2048 + t * 8;
  *(half8*)(wperm + off) = vh;
  *(half8*)(wperm + WLO_OFF + off) = vl;
}

__device__ __forceinline__ void cvt_hilo(const float4 a, const float4 b,
                                         half8& hi, half8& lo) {
  const float v[8] = {a.x, a.y, a.z, a.w, b.x, b.y, b.z, b.w};
#pragma unroll
  for (int j = 0; j < 8; ++j) {
    _Float16 hv = (_Float16)v[j];
    hi[j] = hv;
    lo[j] = (_Float16)(v[j] - (float)hv);
  }
}

// ---------------------------------------------------------------------------
// Fused GRU, software-pipelined:
//  - x/h fp32 loads for kt+1 issued at TOP of compute phase (~144 MFMAs of
//    latency cover), converted to fp16 hi/lo at the compute TAIL; between the
//    two barriers only the 8 ds_write_b128 remain -> no HBM latency or DMA
//    drain on the critical path.
//  - ALL W fragments (hi and lo) load direct global->VGPR; W slice per XCD
//    (nt = bid&7 == XCD) is L2-resident. No global_load_lds -> no vmcnt(0)
//    barrier drain (the m97 structural stall).
// Block tile 128x64, 4 waves 64x32, BK=32, hi/lo 3-term fp16 emulation.
// ---------------------------------------------------------------------------
__global__ __launch_bounds__(256, 2) void gru_fused(
    const float* __restrict__ x, const float* __restrict__ h,
    const _Float16* __restrict__ wperm,
    const float* __restrict__ br, const float* __restrict__ bz,
    const float* __restrict__ bn, float* __restrict__ out) {
  __shared__ __align__(16) _Float16 ldsXh[4096];  // 8 KB each, 32 KB total
  __shared__ __align__(16) _Float16 ldsXl[4096];
  __shared__ __align__(16) _Float16 ldsHh[4096];
  __shared__ __align__(16) _Float16 ldsHl[4096];

  const int t = threadIdx.x;
  const int lane = t & 63;
  const int wv = t >> 6;
  const int wm = wv >> 1;
  const int wn = wv & 1;
  const int bid = blockIdx.x;
  const int nt = bid & 7;   // == XCD under round-robin dispatch: W stays L2-hot
  const int mt = bid >> 3;
  const int m0 = mt * 128;
  const int n0 = nt * 64;
  const _Float16* whi = wperm;
  const _Float16* wlo = wperm + WLO_OFF;

  floatx4 acc_r[4][2] = {};
  floatx4 acc_z[4][2] = {};
  floatx4 acc_in[4][2] = {};
  floatx4 acc_hn[4][2] = {};

  // staging chunks: c in {t, t+256}; row m = 16*(c>>6) + (c&15),
  // k offset = 8*((c&63)>>4); chunk written at base + c*8 halfs.
  const int c0 = t, c1 = t + 256;
  const int l0 = c0 & 63, l1 = c1 & 63;
  const int mA0 = 16 * (c0 >> 6) + (l0 & 15), kA0 = 8 * (l0 >> 4);
  const int mA1 = 16 * (c1 >> 6) + (l1 & 15), kA1 = 8 * (l1 >> 4);
  const float* pxb0 = x + (size_t)(m0 + mA0) * 512 + kA0;
  const float* pxb1 = x + (size_t)(m0 + mA1) * 512 + kA1;
  const float* phb0 = h + (size_t)(m0 + mA0) * 512 + kA0;
  const float* phb1 = h + (size_t)(m0 + mA1) * 512 + kA1;

  // pre-loop: load + convert kt=0 staging data
  half8 sth[4], stl[4];
  cvt_hilo(*(const float4*)pxb0, *(const float4*)(pxb0 + 4), sth[0], stl[0]);
  cvt_hilo(*(const float4*)pxb1, *(const float4*)(pxb1 + 4), sth[1], stl[1]);
  cvt_hilo(*(const float4*)phb0, *(const float4*)(phb0 + 4), sth[2], stl[2]);
  cvt_hilo(*(const float4*)phb1, *(const float4*)(phb1 + 4), sth[3], stl[3]);

  for (int kt = 0; kt < 16; ++kt) {
    __syncthreads();  // barrier A: prev compute done reading LDS (cheap drain)
    *(half8*)(ldsXh + c0 * 8) = sth[0];
    *(half8*)(ldsXh + c1 * 8) = sth[1];
    *(half8*)(ldsHh + c0 * 8) = sth[2];
    *(half8*)(ldsHh + c1 * 8) = sth[3];
    *(half8*)(ldsXl + c0 * 8) = stl[0];
    *(half8*)(ldsXl + c1 * 8) = stl[1];
    *(half8*)(ldsHl + c0 * 8) = stl[2];
    *(half8*)(ldsHl + c1 * 8) = stl[3];
    __syncthreads();  // barrier B: lgkm drain only (no DMA, no global pending)

    // --- prefetch x/h for kt+1 (registers; covered by the MFMA phase) ---
    const int kn = ((kt + 1) & 15) * 32;  // kt=15 wraps harmlessly
    float4 nx0 = *(const float4*)(pxb0 + kn);
    float4 nx1 = *(const float4*)(pxb0 + kn + 4);
    float4 nx2 = *(const float4*)(pxb1 + kn);
    float4 nx3 = *(const float4*)(pxb1 + kn + 4);
    float4 nh0 = *(const float4*)(phb0 + kn);
    float4 nh1 = *(const float4*)(phb0 + kn + 4);
    float4 nh2 = *(const float4*)(phb1 + kn);
    float4 nh3 = *(const float4*)(phb1 + kn + 4);

    // --- compute: 144 MFMA / wave ---
    half8 axh[4], ahh[4];
#pragma unroll
    for (int i = 0; i < 4; ++i) {
      axh[i] = *(const half8*)(ldsXh + ((wm * 4 + i) * 64 + lane) * 8);
      ahh[i] = *(const half8*)(ldsHh + ((wm * 4 + i) * 64 + lane) * 8);
    }
#pragma unroll
    for (int jn = 0; jn < 2; ++jn) {
      const int bo = (wn * 2 + jn) * 512 + lane * 8;
      const size_t tb = ((size_t)(nt * 16 + kt)) * 2048 + bo;
      // B-hi direct from global (L2-hot)
      half8 bh_ir = *(const half8*)(whi + tb + 0 * WSTRIDE);
      half8 bh_hr = *(const half8*)(whi + tb + 1 * WSTRIDE);
      half8 bh_iz = *(const half8*)(whi + tb + 2 * WSTRIDE);
      half8 bh_hz = *(const half8*)(whi + tb + 3 * WSTRIDE);
      half8 bh_in = *(const half8*)(whi + tb + 4 * WSTRIDE);
      half8 bh_hn = *(const half8*)(whi + tb + 5 * WSTRIDE);
      // phase 1: B_hi x (A_hi + A_lo)
#pragma unroll
      for (int i = 0; i < 4; ++i) {
        half8 axl = *(const half8*)(ldsXl + ((wm * 4 + i) * 64 + lane) * 8);
        half8 ahl = *(const half8*)(ldsHl + ((wm * 4 + i) * 64 + lane) * 8);
        acc_r[i][jn]  = __builtin_amdgcn_mfma_f32_16x16x32_f16(axh[i], bh_ir, acc_r[i][jn], 0, 0, 0);
        acc_r[i][jn]  = __builtin_amdgcn_mfma_f32_16x16x32_f16(axl,    bh_ir, acc_r[i][jn], 0, 0, 0);
        acc_r[i][jn]  = __builtin_amdgcn_mfma_f32_16x16x32_f16(ahh[i], bh_hr, acc_r[i][jn], 0, 0, 0);
        acc_r[i][jn]  = __builtin_amdgcn_mfma_f32_16x16x32_f16(ahl,    bh_hr, acc_r[i][jn], 0, 0, 0);
        acc_z[i][jn]  = __builtin_amdgcn_mfma_f32_16x16x32_f16(axh[i], bh_iz, acc_z[i][jn], 0, 0, 0);
        acc_z[i][jn]  = __builtin_amdgcn_mfma_f32_16x16x32_f16(axl,    bh_iz, acc_z[i][jn], 0, 0, 0);
        acc_z[i][jn]  = __builtin_amdgcn_mfma_f32_16x16x32_f16(ahh[i], bh_hz, acc_z[i][jn], 0, 0, 0);
        acc_z[i][jn]  = __builtin_amdgcn_mfma_f32_16x16x32_f16(ahl,    bh_hz, acc_z[i][jn], 0, 0, 0);
        acc_in[i][jn] = __builtin_amdgcn_mfma_f32_16x16x32_f16(axh[i], bh_in, acc_in[i][jn], 0, 0, 0);
        acc_in[i][jn] = __builtin_amdgcn_mfma_f32_16x16x32_f16(axl,    bh_in, acc_in[i][jn], 0, 0, 0);
        acc_hn[i][jn] = __builtin_amdgcn_mfma_f32_16x16x32_f16(ahh[i], bh_hn, acc_hn[i][jn], 0, 0, 0);
        acc_hn[i][jn] = __builtin_amdgcn_mfma_f32_16x16x32_f16(ahl,    bh_hn, acc_hn[i][jn], 0, 0, 0);
      }
      // B-lo direct from global; phase 2: A_hi x B_lo
      half8 bl_ir = *(const half8*)(wlo + tb + 0 * WSTRIDE);
      half8 bl_hr = *(const half8*)(wlo + tb + 1 * WSTRIDE);
      half8 bl_iz = *(const half8*)(wlo + tb + 2 * WSTRIDE);
      half8 bl_hz = *(const half8*)(wlo + tb + 3 * WSTRIDE);
      half8 bl_in = *(const half8*)(wlo + tb + 4 * WSTRIDE);
      half8 bl_hn = *(const half8*)(wlo + tb + 5 * WSTRIDE);
#pragma unroll
      for (int i = 0; i < 4; ++i) {
        acc_r[i][jn]  = __builtin_amdgcn_mfma_f32_16x16x32_f16(axh[i], bl_ir, acc_r[i][jn], 0, 0, 0);
        acc_r[i][jn]  = __builtin_amdgcn_mfma_f32_16x16x32_f16(ahh[i], bl_hr, acc_r[i][jn], 0, 0, 0);
        acc_z[i][jn]  = __builtin_amdgcn_mfma_f32_16x16x32_f16(axh[i], bl_iz, acc_z[i][jn], 0, 0, 0);
        acc_z[i][jn]  = __builtin_amdgcn_mfma_f32_16x16x32_f16(ahh[i], bl_hz, acc_z[i][jn], 0, 0, 0);
        acc_in[i][jn] = __builtin_amdgcn_mfma_f32_16x16x32_f16(axh[i], bl_in, acc_in[i][jn], 0, 0, 0);
        acc_hn[i][jn] = __builtin_amdgcn_mfma_f32_16x16x32_f16(ahh[i], bl_hn, acc_hn[i][jn], 0, 0, 0);
      }
    }

    // --- compute tail: convert prefetched data (off the barrier path) ---
    cvt_hilo(nx0, nx1, sth[0], stl[0]);
    cvt_hilo(nx2, nx3, sth[1], stl[1]);
    cvt_hilo(nh0, nh1, sth[2], stl[2]);
    cvt_hilo(nh2, nh3, sth[3], stl[3]);
  }

  // --- epilogue: gates + h_new. C/D layout: col = lane&15, row = quad*4+reg ---
  const int quad = lane >> 4;
  const int col = lane & 15;
#pragma unroll
  for (int i = 0; i < 4; ++i) {
    const int mbase = m0 + wm * 64 + i * 16 + quad * 4;
#pragma unroll
    for (int jn = 0; jn < 2; ++jn) {
      const int n = n0 + wn * 32 + jn * 16 + col;
      const float vbr = br[n], vbz = bz[n], vbn = bn[n];
#pragma unroll
      for (int r = 0; r < 4; ++r) {
        const int m = mbase + r;
        const float gr = acc_r[i][jn][r] + vbr;
        const float gz = acc_z[i][jn][r] + vbz;
        const float rg = 1.0f / (1.0f + __expf(-gr));
        const float zg = 1.0f / (1.0f + __expf(-gz));
        const float gn = acc_in[i][jn][r] + rg * acc_hn[i][jn][r] + vbn;
        const float e2 = __expf(2.0f * gn);
        const float ntv = 1.0f - 2.0f / (e2 + 1.0f);
        const float hp = h[(size_t)m * 512 + n];
        out[(size_t)m * 512 + n] = (1.0f - zg) * ntv + zg * hp;
      }
    }
  }
}

extern "C" void kernel_launch(void* const* d_in, const int* in_sizes, int n_in,
                              void* d_out, int out_size, void* d_ws, size_t ws_size,
                              hipStream_t stream) {
  const float* x   = (const float*)d_in[0];
  const float* h   = (const float*)d_in[1];
  const float* Wir = (const float*)d_in[2];
  const float* Whr = (const float*)d_in[3];
  const float* br  = (const float*)d_in[4];
  const float* Wiz = (const float*)d_in[5];
  const float* Whz = (const float*)d_in[6];
  const float* bz  = (const float*)d_in[7];
  const float* Win = (const float*)d_in[8];
  const float* Whn = (const float*)d_in[9];
  const float* bn  = (const float*)d_in[10];
  float* out = (float*)d_out;
  _Float16* wperm = (_Float16*)d_ws;  // needs 2 * 6*512*512*2 = 6.3 MB

  permute_w<<<768, 256, 0, stream>>>(Wir, Whr, Wiz, Whz, Win, Whn, wperm);
  gru_fused<<<1024, 256, 0, stream>>>(x, h, wperm, br, bz, bn, out);
}